// Round 1
// baseline (275.088 us; speedup 1.0000x reference)
//
#include <hip/hip_runtime.h>
#include <cstddef>

// Problem constants
#define B_TOT   256
#define IN_CAPS 1152
#define KDIM    8
#define NJ      10
#define ND      16
#define JD      160           // NJ*ND

// Tiling
#define BB      4             // batches per block (W register reuse factor)
#define ISPLIT  8             // i-range splits -> grid = (256/BB)*ISPLIT = 512 blocks (2/CU)
#define IRANGE  (IN_CAPS/ISPLIT)   // 144
#define CI      16            // i chunk per softmax round (== IPAR, 1 i per thread-group)
#define IPAR    16
#define NTHREADS 640          // IPAR * NJ * 4 (d-quads); also == BB*JD for the tail
#define NCHUNK  (IRANGE/CI)        // 9
#define WSTRIDE (NJ*KDIM*ND)       // 1280 floats per i
#define EPSQ    1e-7f

__device__ __forceinline__ float dot4(float4 a, float4 b) {
    return a.x*b.x + a.y*b.y + a.z*b.z + a.w*b.w;
}

// One routing iteration: s_out[b,j,d] = sum_i c[b,i,j] * u_hat[b,i,j,d]
// u_hat recomputed on the fly from x (LDS, staged once) and W (global, L2-resident
// per XCD: isp == blockIdx&7 == XCD id -> each XCD touches only its 0.74 MB W slice).
// ITER==1: c uniform (softmax of zeros) = 0.1, applied as premul at the end.
// ITER==2: logits = u_hat . v1,        v1 = squash(s1)         (computed in-head)
// ITER==3: logits = u_hat . (v1+v2),   v2 = squash(s2)         (linearity of b-update)
template<int ITER>
__global__ __launch_bounds__(NTHREADS, 5)   // 5 waves/EU -> 2 blocks/CU, VGPR <= 102
void iter_kernel(const float* __restrict__ x, const float* __restrict__ Wt,
                 const float* __restrict__ s1, const float* __restrict__ s2,
                 float* __restrict__ s_out)
{
    const int g   = blockIdx.x >> 3;       // b-group 0..63
    const int isp = blockIdx.x & 7;        // i-split == XCD id (round-robin dispatch)
    const int b0  = g * BB;
    const int i_begin = isp * IRANGE;

    const int t = threadIdx.x;
    const int i_par = t / 40;              // 0..15
    const int r  = t - i_par * 40;
    const int j  = r >> 2;                 // 0..9
    const int dq = r & 3;                  // 0..3  (owns d = dq*4..dq*4+3)

    __shared__ float x_lds[BB][IRANGE][KDIM];   // 18.0 KB  (whole slice, staged once)
    __shared__ float logit_lds[BB][CI][NJ];     // 2.5 KB
    __shared__ float c_lds[BB][CI][NJ];         // 2.5 KB
    __shared__ float s_lds[BB][JD];             // 2.5 KB

    // head: v for this thread's (j, dq) — fused squash of previous iteration(s)
    float4 vs[BB];
    if (ITER >= 2) {
        #pragma unroll
        for (int bb = 0; bb < BB; ++bb) {
            const float4 a = *(const float4*)(s1 + (size_t)(b0 + bb) * JD + j * ND + dq * 4);
            float q2 = dot4(a, a);
            q2 += __shfl_xor(q2, 1);           // sum over the 4-lane d-quad group (16 d)
            q2 += __shfl_xor(q2, 2);
            const float sc = q2 / (1.f + q2) / sqrtf(q2 + EPSQ);
            vs[bb] = make_float4(a.x * sc, a.y * sc, a.z * sc, a.w * sc);
            if (ITER == 3) {
                const float4 bv = *(const float4*)(s2 + (size_t)(b0 + bb) * JD + j * ND + dq * 4);
                float r2 = dot4(bv, bv);
                r2 += __shfl_xor(r2, 1);
                r2 += __shfl_xor(r2, 2);
                const float sc2 = r2 / (1.f + r2) / sqrtf(r2 + EPSQ);
                vs[bb].x += bv.x * sc2; vs[bb].y += bv.y * sc2;
                vs[bb].z += bv.z * sc2; vs[bb].w += bv.w * sc2;
            }
        }
    }

    // stage entire x slice: BB * 288 float4, contiguous & coalesced (2 rounds)
    {
        const int NF = (IRANGE * KDIM) / 4;    // 288 float4 per batch
        for (int idx = t; idx < BB * NF; idx += NTHREADS) {
            const int bb = idx / NF;
            const int f  = idx - bb * NF;
            ((float4*)&x_lds[bb][0][0])[f] =
                ((const float4*)(x + (size_t)(b0 + bb) * IN_CAPS * KDIM
                                   + (size_t)i_begin * KDIM))[f];
        }
    }
    __syncthreads();

    float4 s_acc[BB];
    #pragma unroll
    for (int bb = 0; bb < BB; ++bb) s_acc[bb] = make_float4(0.f, 0.f, 0.f, 0.f);

    const float* wp = Wt + (size_t)((i_begin + i_par) * NJ + j) * (KDIM * ND) + dq * 4;

    for (int c = 0; c < NCHUNK; ++c) {
        // W row fragment for this thread's i: 8 independent 16B loads in flight
        float4 w[KDIM];
        #pragma unroll
        for (int k = 0; k < KDIM; ++k)
            w[k] = *(const float4*)(wp + k * ND);

        const int il = c * CI + i_par;

        // u_hat fragments in registers (one i per thread, 4 batches)
        float4 u[BB];
        #pragma unroll
        for (int bb = 0; bb < BB; ++bb) {
            float xs[KDIM];
            *(float4*)&xs[0] = *(const float4*)&x_lds[bb][il][0];   // ds_read_b128
            *(float4*)&xs[4] = *(const float4*)&x_lds[bb][il][4];   // ds_read_b128
            float4 uu = make_float4(0.f, 0.f, 0.f, 0.f);
            #pragma unroll
            for (int k = 0; k < KDIM; ++k) {
                uu.x += xs[k] * w[k].x;
                uu.y += xs[k] * w[k].y;
                uu.z += xs[k] * w[k].z;
                uu.w += xs[k] * w[k].w;
            }
            u[bb] = uu;
        }

        if (ITER == 1) {
            // uniform c: just accumulate (premultiplied by 0.1 at the end).
            // NO barriers in this loop at all -> free software pipelining.
            #pragma unroll
            for (int bb = 0; bb < BB; ++bb) {
                s_acc[bb].x += u[bb].x; s_acc[bb].y += u[bb].y;
                s_acc[bb].z += u[bb].z; s_acc[bb].w += u[bb].w;
            }
        } else {
            // logits -> LDS
            #pragma unroll
            for (int bb = 0; bb < BB; ++bb) {
                float lg = dot4(u[bb], vs[bb]);
                lg += __shfl_xor(lg, 1);       // reduce over the 4-lane d-quad group
                lg += __shfl_xor(lg, 2);
                if (dq == 0) logit_lds[bb][i_par][j] = lg;
            }
            __syncthreads();

            // softmax over j: exactly one entry per thread (640 == BB*CI*NJ)
            {
                const int bb  = t / (CI * NJ);
                const int rem = t - bb * (CI * NJ);
                const int il2 = rem / NJ;
                const int jj  = rem - il2 * NJ;
                float lv[NJ];
                float m = -1e30f;
                #pragma unroll
                for (int q = 0; q < NJ; ++q) { lv[q] = logit_lds[bb][il2][q]; m = fmaxf(m, lv[q]); }
                float ssum = 0.f, ex = 0.f;
                #pragma unroll
                for (int q = 0; q < NJ; ++q) {
                    const float e = __expf(lv[q] - m);
                    ssum += e;
                    if (q == jj) ex = e;       // static unroll -> cndmask, no scratch
                }
                c_lds[bb][il2][jj] = ex / ssum;
            }
            __syncthreads();

            // s += c * u_hat (u_hat still in registers)
            #pragma unroll
            for (int bb = 0; bb < BB; ++bb) {
                const float cc = c_lds[bb][i_par][j];
                s_acc[bb].x += cc * u[bb].x; s_acc[bb].y += cc * u[bb].y;
                s_acc[bb].z += cc * u[bb].z; s_acc[bb].w += cc * u[bb].w;
            }
        }

        wp += (size_t)CI * WSTRIDE;
    }

    // block-level reduction over i_par groups via LDS, then one global atomic each
    ((float*)s_lds)[t] = 0.f;   // NTHREADS == BB*JD
    __syncthreads();
    const float premul = (ITER == 1) ? 0.1f : 1.0f;   // softmax(zeros) over 10 caps
    #pragma unroll
    for (int bb = 0; bb < BB; ++bb) {
        atomicAdd(&s_lds[bb][j * ND + dq * 4 + 0], s_acc[bb].x * premul);
        atomicAdd(&s_lds[bb][j * ND + dq * 4 + 1], s_acc[bb].y * premul);
        atomicAdd(&s_lds[bb][j * ND + dq * 4 + 2], s_acc[bb].z * premul);
        atomicAdd(&s_lds[bb][j * ND + dq * 4 + 3], s_acc[bb].w * premul);
    }
    __syncthreads();
    {
        const int bb = t / JD;
        const int jd = t - bb * JD;
        unsafeAtomicAdd(&s_out[(size_t)(b0 + bb) * JD + jd], s_lds[bb][jd]);
    }
}

// final squash per (b,j): v = s * s2/(1+s2)/sqrt(s2+eps); 16-lane shuffle reduction.
__global__ __launch_bounds__(256)
void squash_kernel(const float* __restrict__ s, float* __restrict__ out)
{
    const int idx = blockIdx.x * 256 + threadIdx.x;   // grid 160 -> exactly 40960
    const float sv = s[idx];
    float sq = sv * sv;
    sq += __shfl_xor(sq, 1);
    sq += __shfl_xor(sq, 2);
    sq += __shfl_xor(sq, 4);
    sq += __shfl_xor(sq, 8);    // sum over the 16 d-lanes (16-aligned in wave)
    const float scale = sq / (1.0f + sq) / sqrtf(sq + EPSQ);
    out[idx] = sv * scale;
}

extern "C" void kernel_launch(void* const* d_in, const int* in_sizes, int n_in,
                              void* d_out, int out_size, void* d_ws, size_t ws_size,
                              hipStream_t stream)
{
    const float* x  = (const float*)d_in[0];   // [256,1152,8]
    const float* Wt = (const float*)d_in[1];   // [1152,10,8,16]
    float* out = (float*)d_out;                // [256,10,16]
    float* s1  = (float*)d_ws;                 // 40960 floats each
    float* s2  = s1 + (size_t)B_TOT * JD;
    float* s3  = s2 + (size_t)B_TOT * JD;

    // ws is re-poisoned before every launch: zero the three s accumulators (480 KB)
    hipMemsetAsync(d_ws, 0, 3 * (size_t)B_TOT * JD * sizeof(float), stream);

    dim3 grid((B_TOT / BB) * ISPLIT), blk(NTHREADS);

    iter_kernel<1><<<grid, blk, 0, stream>>>(x, Wt, nullptr, nullptr, s1);  // s1 = sum(0.1*u)
    iter_kernel<2><<<grid, blk, 0, stream>>>(x, Wt, s1, nullptr, s2);       // v1 in-head
    iter_kernel<3><<<grid, blk, 0, stream>>>(x, Wt, s1, s2, s3);            // v1+v2 in-head
    squash_kernel<<<dim3((B_TOT * JD) / 256), dim3(256), 0, stream>>>(s3, out);
}